// Round 9
// baseline (727.735 us; speedup 1.0000x reference)
//
#include <hip/hip_runtime.h>
#include <hip/hip_bf16.h>

// GraphSAGE 3-layer, N=50000 nodes, E=400000 edges, dims 512->512->512->128.
// Round 15 -> 16 (resubmit; R8 bench was an infra failure "container failed
// twice" -- source re-audited for OOB/crash vectors, none found):
// AGGREGATE-FIRST restructure (linearity: mean(x_j)@W_l == mean(x_j)@W_l
// applied before the transform):
//   per layer: mx = gather_mean(h);  h' = act([h | mx] @ [W_r; W_l] + b)
// -> ONE GEMM per layer, K=1024, fused bias+relu epilogue, 50MB C-write
//    (was 100MB), no Yr buffer/read, no separate gather-ADD kernel.
// -> layer 3: dense [M][128] GEMM output + elementwise log_softmax; the
//    fragmented 256B-random lsm gather (R4-proven bad pattern) is GONE.
// -> K=1024 doubles iters/block (32) amortizing per-block overhead.
// GEMM kernel = R1's verified 128x128/4-wave/dbuf/global_load_lds template
// with a two-base A stage (k<512 -> h, k>=512 -> mx; wave-uniform branch).

#define N_NODES 50000
#define N_EDGES 400000

typedef unsigned short u16;
typedef unsigned int u32;
typedef __attribute__((ext_vector_type(8))) short short8;
typedef __attribute__((ext_vector_type(4))) float floatx4;

#define ASYNC16(g, l)                                                      \
    __builtin_amdgcn_global_load_lds(                                      \
        (const __attribute__((address_space(1))) void*)(g),                \
        (__attribute__((address_space(3))) void*)(l), 16, 0, 0)

__device__ __forceinline__ u16 f32_to_bf16(float f) {
    u32 u = __float_as_uint(f);
    u32 r = 0x7FFFu + ((u >> 16) & 1u);
    return (u16)((u + r) >> 16);
}
__device__ __forceinline__ float bf16_to_f32(u32 lo16) {
    return __uint_as_float(lo16 << 16);
}

__global__ __launch_bounds__(256) void zero4_kernel(float4* __restrict__ p, int n4) {
    int i = blockIdx.x * 256 + threadIdx.x;
    if (i < n4) p[i] = make_float4(0.f, 0.f, 0.f, 0.f);
}

__global__ __launch_bounds__(256) void hist_kernel(const int* __restrict__ dst,
                                                   int* __restrict__ deg, int E) {
    int e = blockIdx.x * 256 + threadIdx.x;
    if (e < E) atomicAdd(&deg[dst[e]], 1);
}

__global__ __launch_bounds__(256) void scan_reduce(const int* __restrict__ v,
                                                   int* __restrict__ bsums, int n) {
    __shared__ int sh[256];
    int i = blockIdx.x * 256 + threadIdx.x;
    sh[threadIdx.x] = (i < n) ? v[i] : 0;
    __syncthreads();
    for (int off = 128; off > 0; off >>= 1) {
        if (threadIdx.x < off) sh[threadIdx.x] += sh[threadIdx.x + off];
        __syncthreads();
    }
    if (threadIdx.x == 0) bsums[blockIdx.x] = sh[0];
}

__global__ __launch_bounds__(256) void scan_sums(int* __restrict__ bsums, int nb) {
    __shared__ int sh[256];
    int t = threadIdx.x;
    int val = (t < nb) ? bsums[t] : 0;
    sh[t] = val;
    __syncthreads();
    for (int off = 1; off < 256; off <<= 1) {
        int v = (t >= off) ? sh[t - off] : 0;
        __syncthreads();
        sh[t] += v;
        __syncthreads();
    }
    if (t < nb) bsums[t] = sh[t] - val;
}

__global__ __launch_bounds__(256) void scan_final(int* __restrict__ v,
                                                  const int* __restrict__ bsums, int n) {
    __shared__ int sh[256];
    int t = threadIdx.x;
    int i = blockIdx.x * 256 + t;
    int val = (i < n) ? v[i] : 0;
    sh[t] = val;
    __syncthreads();
    for (int off = 1; off < 256; off <<= 1) {
        int x = (t >= off) ? sh[t - off] : 0;
        __syncthreads();
        sh[t] += x;
        __syncthreads();
    }
    int excl = sh[t] - val + bsums[blockIdx.x];
    if (i < n) v[i] = excl;
    if (i == n - 1) v[n] = excl + val;
}

__global__ __launch_bounds__(256) void fill_kernel(const int* __restrict__ src,
                                                   const int* __restrict__ dst,
                                                   const int* __restrict__ row_start,
                                                   int* __restrict__ cursor,
                                                   int* __restrict__ csr_src, int E) {
    int e = blockIdx.x * 256 + threadIdx.x;
    if (e < E) {
        int d = dst[e];
        int pos = row_start[d] + atomicAdd(&cursor[d], 1);
        csr_src[pos] = src[e];
    }
}

// f32 [n8*8] -> bf16, 8 elems/thread
__global__ __launch_bounds__(256) void convert_bf16(const float* __restrict__ in,
                                                    u16* __restrict__ out, int n8) {
    int i = blockIdx.x * 256 + threadIdx.x;
    if (i >= n8) return;
    const float4* p = (const float4*)in + (size_t)i * 2;
    float4 v0 = p[0], v1 = p[1];
    uint4 o;
    o.x = (u32)f32_to_bf16(v0.x) | ((u32)f32_to_bf16(v0.y) << 16);
    o.y = (u32)f32_to_bf16(v0.z) | ((u32)f32_to_bf16(v0.w) << 16);
    o.z = (u32)f32_to_bf16(v1.x) | ((u32)f32_to_bf16(v1.y) << 16);
    o.w = (u32)f32_to_bf16(v1.z) | ((u32)f32_to_bf16(v1.w) << 16);
    ((uint4*)out)[i] = o;
}

// W [K][N] f32 -> WT [N][kstride] bf16 at column offset koff, 32x32 tiles.
__global__ __launch_bounds__(256) void transpose_w(const float* __restrict__ W,
                                                   u16* __restrict__ WT,
                                                   int K, int N, int kstride, int koff) {
    __shared__ float t[32][33];
    int n0 = blockIdx.x * 32, k0 = blockIdx.y * 32;
    int c = threadIdx.x & 31, r0 = threadIdx.x >> 5;
    for (int r = r0; r < 32; r += 8)
        t[r][c] = W[(size_t)(k0 + r) * N + n0 + c];
    __syncthreads();
    for (int r = r0; r < 32; r += 8)
        WT[(size_t)(n0 + r) * kstride + koff + k0 + c] = f32_to_bf16(t[c][r]);
}

// C = act([A0|A1] @ BT' + bias), K=1024 (A0 = k<512 half, A1 = k>=512 half,
// both [M][512] k-contig; BT [N][1024] k-contig). 128x128 tile, 4 waves,
// dbuf LDS, global_load_lds staging (lane-linear dest, source-swizzled,
// rule-21 involution), 1 barrier/iter, swapped-operand MFMA, fused
// bias(+relu) epilogue, bf16 out [M][N].
__global__ __launch_bounds__(256) void gemm_bias(
    const u16* __restrict__ A0, const u16* __restrict__ A1,
    const u16* __restrict__ BT, const float* __restrict__ bias,
    u16* __restrict__ C, int M, int N, int nStrips, int nCols, int relu) {
    __shared__ u16 As[2][4096];  // 128 rows x 32 u16 (64B), lane-linear
    __shared__ u16 Bs[2][4096];

    const int grp = 8 * nCols;
    int b = blockIdx.x;
    int strip = (b / grp) * 8 + (b & 7);   // col-tiles of a strip share b%8 -> XCD
    int colt = (b % grp) >> 3;
    if (strip >= nStrips) return;
    const int row0 = strip * 128, col0 = colt * 128;

    const int t = threadIdx.x;
    const int w = t >> 6, lane = t & 63;
    const int wm = (w >> 1) * 64, wn = (w & 1) * 64;
    const int l15 = lane & 15, kq = lane >> 4;
    const int swz = (l15 >> 1) & 3;        // fragment-read swizzle bits

    floatx4 acc[4][4];
#pragma unroll
    for (int i = 0; i < 4; ++i)
#pragma unroll
        for (int j = 0; j < 4; ++j) acc[i][j] = floatx4{0.f, 0.f, 0.f, 0.f};

    // Staging geometry: thread t -> rows sr, sr+64; 16B chunk (t&3).
    // LDS dest lane-linear per wave (HW req); bank swizzle on GLOBAL source
    // (position sc holds global chunk sc^swzS; reader uses kq^swz).
    const int sr = t >> 2;
    const int sc = t & 3;
    const int swzS = (sr >> 1) & 3;        // same bits for sr and sr+64
    const size_t aA0 = (size_t)min(row0 + sr, M - 1) * 512 + (sc ^ swzS) * 8;
    const size_t aA1 = (size_t)min(row0 + 64 + sr, M - 1) * 512 + (sc ^ swzS) * 8;
    const size_t bB0 = (size_t)(col0 + sr) * 1024 + (sc ^ swzS) * 8;
    const size_t bB1 = (size_t)(col0 + 64 + sr) * 1024 + (sc ^ swzS) * 8;
    const int d0 = w * 512;        // u16 index: wave-uniform LDS dest, part 0
    const int d1 = 2048 + w * 512; // rows +64

    auto stage = [&](int it, int buf) {
        const u16* __restrict__ Asrc = (it < 16) ? A0 : A1;  // wave-uniform
        const int effA = (it & 15) * 32;
        const int effB = it * 32;
        ASYNC16(Asrc + aA0 + effA, &As[buf][d0]);
        ASYNC16(Asrc + aA1 + effA, &As[buf][d1]);
        ASYNC16(BT + bB0 + effB, &Bs[buf][d0]);
        ASYNC16(BT + bB1 + effB, &Bs[buf][d1]);
    };

    stage(0, 0);
    __syncthreads();  // vmcnt(0) drain: buf0 ready
    for (int it = 0; it < 32; ++it) {
        const int buf = it & 1;
        if (it + 1 < 32) stage(it + 1, buf ^ 1);  // in flight across the MFMAs

        const int kc = (kq ^ swz) * 8;      // swizzled chunk for this lane
        short8 a[4], bfr[4];
#pragma unroll
        for (int mt = 0; mt < 4; ++mt)
            a[mt] = *(const short8*)&As[buf][(wm + mt * 16 + l15) * 32 + kc];
#pragma unroll
        for (int nt = 0; nt < 4; ++nt)
            bfr[nt] = *(const short8*)&Bs[buf][(wn + nt * 16 + l15) * 32 + kc];
        // Swapped operands: D = C^T; lane l15 = C-row, regs = 4 consecutive cols
#pragma unroll
        for (int mt = 0; mt < 4; ++mt)
#pragma unroll
            for (int nt = 0; nt < 4; ++nt)
                acc[mt][nt] = __builtin_amdgcn_mfma_f32_16x16x32_bf16(
                    bfr[nt], a[mt], acc[mt][nt], 0, 0, 0);
        __syncthreads();  // drains this iter's stage -> buf^1 ready
    }

    // Epilogue: row = row0+wm+mt*16+l15, cols = col0+wn+nt*16+kq*4..+3;
    // fused bias (+relu), bf16 pack, uint2 store.
#pragma unroll
    for (int mt = 0; mt < 4; ++mt) {
        int row = row0 + wm + mt * 16 + l15;
        if (row >= M) continue;
#pragma unroll
        for (int nt = 0; nt < 4; ++nt) {
            int c0 = col0 + wn + nt * 16 + kq * 4;
            float4 bv = *(const float4*)(bias + c0);
            float v0 = acc[mt][nt][0] + bv.x;
            float v1 = acc[mt][nt][1] + bv.y;
            float v2 = acc[mt][nt][2] + bv.z;
            float v3 = acc[mt][nt][3] + bv.w;
            if (relu) {
                v0 = fmaxf(v0, 0.f); v1 = fmaxf(v1, 0.f);
                v2 = fmaxf(v2, 0.f); v3 = fmaxf(v3, 0.f);
            }
            uint2 o;
            o.x = (u32)f32_to_bf16(v0) | ((u32)f32_to_bf16(v1) << 16);
            o.y = (u32)f32_to_bf16(v2) | ((u32)f32_to_bf16(v3) << 16);
            *(uint2*)(C + (size_t)row * N + c0) = o;
        }
    }
}

__device__ __forceinline__ void acc8(float* a, uint4 v) {
    a[0] += bf16_to_f32(v.x & 0xffffu); a[1] += bf16_to_f32(v.x >> 16);
    a[2] += bf16_to_f32(v.y & 0xffffu); a[3] += bf16_to_f32(v.y >> 16);
    a[4] += bf16_to_f32(v.z & 0xffffu); a[5] += bf16_to_f32(v.z >> 16);
    a[6] += bf16_to_f32(v.w & 0xffffu); a[7] += bf16_to_f32(v.w >> 16);
}

// mx[node] = mean_{j in N(node)} S[j], D=512 bf16. One wave per node;
// lane covers 8 cols (uint4); neighbor loop 4-deep.
__global__ __launch_bounds__(256) void gather_mean512(
    const u16* __restrict__ S,
    const int* __restrict__ row_start, const int* __restrict__ csr_src,
    u16* __restrict__ mx, int M) {
    int node = (blockIdx.x * 256 + threadIdx.x) >> 6;
    int lane = threadIdx.x & 63;
    if (node >= M) return;
    int beg = row_start[node], end = row_start[node + 1];
    float a[8] = {0.f, 0.f, 0.f, 0.f, 0.f, 0.f, 0.f, 0.f};
    for (int c = beg; c < end; c += 64) {
        int nb = min(64, end - c);
        int eid = (lane < nb) ? csr_src[c + lane] : 0;
        int i = 0;
        for (; i + 4 <= nb; i += 4) {
            int s0 = __shfl(eid, i);
            int s1 = __shfl(eid, i + 1);
            int s2 = __shfl(eid, i + 2);
            int s3 = __shfl(eid, i + 3);
            uint4 v0 = ((const uint4*)(S + (size_t)s0 * 512))[lane];
            uint4 v1 = ((const uint4*)(S + (size_t)s1 * 512))[lane];
            uint4 v2 = ((const uint4*)(S + (size_t)s2 * 512))[lane];
            uint4 v3 = ((const uint4*)(S + (size_t)s3 * 512))[lane];
            acc8(a, v0); acc8(a, v1); acc8(a, v2); acc8(a, v3);
        }
        for (; i < nb; ++i) {
            int s = __shfl(eid, i);
            uint4 v = ((const uint4*)(S + (size_t)s * 512))[lane];
            acc8(a, v);
        }
    }
    float inv = 1.0f / fmaxf((float)(end - beg), 1.0f);
    uint4 o;
    o.x = (u32)f32_to_bf16(a[0] * inv) | ((u32)f32_to_bf16(a[1] * inv) << 16);
    o.y = (u32)f32_to_bf16(a[2] * inv) | ((u32)f32_to_bf16(a[3] * inv) << 16);
    o.z = (u32)f32_to_bf16(a[4] * inv) | ((u32)f32_to_bf16(a[5] * inv) << 16);
    o.w = (u32)f32_to_bf16(a[6] * inv) | ((u32)f32_to_bf16(a[7] * inv) << 16);
    ((uint4*)(mx + (size_t)node * 512))[lane] = o;
}

// out[node] = log_softmax(Y[node]), D=128 bf16 in (bias already fused),
// f32 out. 16 lanes per node (4 nodes/wave); lane covers 8 cols. Dense rows.
__global__ __launch_bounds__(256) void lsm_dense128(
    const u16* __restrict__ Y, float* __restrict__ out, int M) {
    int node = blockIdx.x * 16 + (threadIdx.x >> 4);
    int li = threadIdx.x & 15;
    if (node >= M) return;
    uint4 yv = ((const uint4*)(Y + (size_t)node * 128))[li];
    float v[8];
    v[0] = bf16_to_f32(yv.x & 0xffffu); v[1] = bf16_to_f32(yv.x >> 16);
    v[2] = bf16_to_f32(yv.y & 0xffffu); v[3] = bf16_to_f32(yv.y >> 16);
    v[4] = bf16_to_f32(yv.z & 0xffffu); v[5] = bf16_to_f32(yv.z >> 16);
    v[6] = bf16_to_f32(yv.w & 0xffffu); v[7] = bf16_to_f32(yv.w >> 16);
    float m = v[0];
#pragma unroll
    for (int j = 1; j < 8; ++j) m = fmaxf(m, v[j]);
#pragma unroll
    for (int off = 1; off < 16; off <<= 1) m = fmaxf(m, __shfl_xor(m, off));
    float s = 0.f;
#pragma unroll
    for (int j = 0; j < 8; ++j) s += expf(v[j] - m);
#pragma unroll
    for (int off = 1; off < 16; off <<= 1) s += __shfl_xor(s, off);
    float ls = m + logf(s);
    float* p = out + (size_t)node * 128 + li * 8;
    *(float4*)p       = make_float4(v[0] - ls, v[1] - ls, v[2] - ls, v[3] - ls);
    *(float4*)(p + 4) = make_float4(v[4] - ls, v[5] - ls, v[6] - ls, v[7] - ls);
}

extern "C" void kernel_launch(void* const* d_in, const int* in_sizes, int n_in,
                              void* d_out, int out_size, void* d_ws, size_t ws_size,
                              hipStream_t stream) {
    const float* x    = (const float*)d_in[0];
    const int*   ei   = (const int*)d_in[1];
    const float* W1_l = (const float*)d_in[2];
    const float* b1   = (const float*)d_in[3];
    const float* W1_r = (const float*)d_in[4];
    const float* W2_l = (const float*)d_in[5];
    const float* b2   = (const float*)d_in[6];
    const float* W2_r = (const float*)d_in[7];
    const float* W3_l = (const float*)d_in[8];
    const float* b3   = (const float*)d_in[9];
    const float* W3_r = (const float*)d_in[10];
    float* out = (float*)d_out;

    const int* src = ei;
    const int* dst = ei + N_EDGES;

    // Workspace layout (bytes from base):
    char* base = (char*)d_ws;
    int* row_start = (int*)(base);                    // 50052 ints
    int* cursor    = (int*)(base + 200208);           // 50052 ints
    int* bsums     = (int*)(base + 400416);           // 512 ints
    int* csr_src   = (int*)(base + 402464);           // 400000 ints -> end 2002464
    u16* xb  = (u16*)(base + 2002464);                // [M][512] bf16
    u16* h1b = (u16*)(base + 53202464);               // [M][512]
    u16* h2b = (u16*)(base + 104402464);              // [M][512]
    u16* mx  = (u16*)(base + 155602464);              // [M][512] (shared mean buf)
    u16* y3  = (u16*)(base + 206802464);              // [M][128] bf16
    u16* w1T = (u16*)(base + 219602464);              // [512][1024]
    u16* w2T = (u16*)(base + 220651040);              // [512][1024]
    u16* w3T = (u16*)(base + 221699616);              // [128][1024] -> end 221961760

    const int E = N_EDGES, M = N_NODES;
    const int nblk = (M + 255) / 256;

    // ---- CSR build ----
    zero4_kernel<<<(25154 + 255) / 256, 256, 0, stream>>>((float4*)d_ws, 25154);
    hist_kernel<<<(E + 255) / 256, 256, 0, stream>>>(dst, row_start, E);
    scan_reduce<<<nblk, 256, 0, stream>>>(row_start, bsums, M);
    scan_sums<<<1, 256, 0, stream>>>(bsums, nblk);
    scan_final<<<nblk, 256, 0, stream>>>(row_start, bsums, M);
    fill_kernel<<<(E + 255) / 256, 256, 0, stream>>>(src, dst, row_start, cursor,
                                                     csr_src, E);

    // ---- conversions: x -> bf16; weights -> WT [N][1024] bf16 ([W_r | W_l]
    //      along k: k<512 multiplies h, k>=512 multiplies mean) ----
    convert_bf16<<<(3200000 + 255) / 256, 256, 0, stream>>>(x, xb, 3200000);
    transpose_w<<<dim3(16, 16), 256, 0, stream>>>(W1_r, w1T, 512, 512, 1024, 0);
    transpose_w<<<dim3(16, 16), 256, 0, stream>>>(W1_l, w1T, 512, 512, 1024, 512);
    transpose_w<<<dim3(16, 16), 256, 0, stream>>>(W2_r, w2T, 512, 512, 1024, 0);
    transpose_w<<<dim3(16, 16), 256, 0, stream>>>(W2_l, w2T, 512, 512, 1024, 512);
    transpose_w<<<dim3(4, 16), 256, 0, stream>>>(W3_r, w3T, 512, 128, 1024, 0);
    transpose_w<<<dim3(4, 16), 256, 0, stream>>>(W3_l, w3T, 512, 128, 1024, 512);

    const int nStrips = (M + 127) / 128;                 // 391
    const int gridN512 = ((nStrips + 7) / 8) * 8 * 4;    // 1568 (nCols=4)
    const int gridN128 = ((nStrips + 7) / 8) * 8 * 1;    // 392  (nCols=1)
    const int gblocks = (M * 64 + 255) / 256;            // wave/node
    const int g16blocks = (M + 15) / 16;                 // 16 lanes/node

    // ---- layer 1: mx = mean(x); h1 = relu([x|mx]@[W1r;W1l] + b1) ----
    gather_mean512<<<gblocks, 256, 0, stream>>>(xb, row_start, csr_src, mx, M);
    gemm_bias<<<gridN512, 256, 0, stream>>>(xb, mx, w1T, b1, h1b, M, 512,
                                            nStrips, 4, 1);
    // ---- layer 2 ----
    gather_mean512<<<gblocks, 256, 0, stream>>>(h1b, row_start, csr_src, mx, M);
    gemm_bias<<<gridN512, 256, 0, stream>>>(h1b, mx, w2T, b2, h2b, M, 512,
                                            nStrips, 4, 1);
    // ---- layer 3: y3 = [h2|mx]@[W3r;W3l] + b3; out = log_softmax(y3) ----
    gather_mean512<<<gblocks, 256, 0, stream>>>(h2b, row_start, csr_src, mx, M);
    gemm_bias<<<gridN128, 256, 0, stream>>>(h2b, mx, w3T, b3, y3, M, 128,
                                            nStrips, 1, 0);
    lsm_dense128<<<g16blocks, 256, 0, stream>>>(y3, out, M);
}

// Round 10
// 624.023 us; speedup vs baseline: 1.1662x; 1.1662x over previous
//
#include <hip/hip_runtime.h>
#include <hip/hip_bf16.h>

// GraphSAGE 3-layer, N=50000 nodes, E=400000 edges, dims 512->512->512->128.
// Round 17: revert aggregate-first (R9 regression); GEMM ported to the
// m201-style 8-phase lockstep schedule at the verified geometry:
//   256x256 tile, BK=64, 512 thr (8 waves 2Mx4N, per-wave 128x64, acc[8][4]),
//   128KB dynamic LDS = 2 K-tile slots x (A 32KB + B 32KB).
//   Per K-tile: 4 phases {stage 2 rounds, ds_read A-frags, 16 MFMA(setprio),
//   raw s_barrier}; boundary = vmcnt(2) + s_barrier (counted -- loads stay in
//   flight across barriers; NEVER __syncthreads, which drains vmcnt(0)).
//   Staging death-ledger (region overwritten >=1 barrier after last read):
//     A rows [q*32,(q+1)*32) of a K-tile die after its phase q;
//     B dies after phase 3. Schedule (during kt, slot s=kt&1, o=s^1):
//       ph0: stage kt+1 A rounds 1,3 -> o (kt-1 rows 64-127/192-255, dead)
//       ph1: stage kt+1 B rounds 0,2 -> o (kt-1 B dead)
//       ph2: stage kt+1 B rounds 1,3 -> o
//       ph3: stage kt+2 A rounds 0,2 -> s (kt rows 0-63/128-191 dead @ph1)
//       boundary: vmcnt(2) [= ph3's 2 rounds outstanding => kt+1 landed]
//     kt+1's A rounds 0,2 were staged at kt-1 ph3 (consistent ring).
//   Bank conflicts: BK=64 row split into two 64B kk-planes; R1's verified
//   2-bit involution per plane (src chunk (lane&3)^((lane>>3)&3), read chunk
//   kq^((l15>>1)&3)) -> 2-way max (free).
// Gathers / conversions / CSR: R7 verbatim (best: 656us).

#define N_NODES 50000
#define N_EDGES 400000

typedef unsigned short u16;
typedef unsigned int u32;
typedef __attribute__((ext_vector_type(8))) short short8;
typedef __attribute__((ext_vector_type(4))) float floatx4;

#define ASYNC16(g, l)                                                      \
    __builtin_amdgcn_global_load_lds(                                      \
        (const __attribute__((address_space(1))) void*)(g),                \
        (__attribute__((address_space(3))) void*)(l), 16, 0, 0)

__device__ __forceinline__ u16 f32_to_bf16(float f) {
    u32 u = __float_as_uint(f);
    u32 r = 0x7FFFu + ((u >> 16) & 1u);
    return (u16)((u + r) >> 16);
}
__device__ __forceinline__ float bf16_to_f32(u32 lo16) {
    return __uint_as_float(lo16 << 16);
}

__global__ __launch_bounds__(256) void zero4_kernel(float4* __restrict__ p, int n4) {
    int i = blockIdx.x * 256 + threadIdx.x;
    if (i < n4) p[i] = make_float4(0.f, 0.f, 0.f, 0.f);
}

__global__ __launch_bounds__(256) void hist_kernel(const int* __restrict__ dst,
                                                   int* __restrict__ deg, int E) {
    int e = blockIdx.x * 256 + threadIdx.x;
    if (e < E) atomicAdd(&deg[dst[e]], 1);
}

__global__ __launch_bounds__(256) void scan_reduce(const int* __restrict__ v,
                                                   int* __restrict__ bsums, int n) {
    __shared__ int sh[256];
    int i = blockIdx.x * 256 + threadIdx.x;
    sh[threadIdx.x] = (i < n) ? v[i] : 0;
    __syncthreads();
    for (int off = 128; off > 0; off >>= 1) {
        if (threadIdx.x < off) sh[threadIdx.x] += sh[threadIdx.x + off];
        __syncthreads();
    }
    if (threadIdx.x == 0) bsums[blockIdx.x] = sh[0];
}

__global__ __launch_bounds__(256) void scan_sums(int* __restrict__ bsums, int nb) {
    __shared__ int sh[256];
    int t = threadIdx.x;
    int val = (t < nb) ? bsums[t] : 0;
    sh[t] = val;
    __syncthreads();
    for (int off = 1; off < 256; off <<= 1) {
        int v = (t >= off) ? sh[t - off] : 0;
        __syncthreads();
        sh[t] += v;
        __syncthreads();
    }
    if (t < nb) bsums[t] = sh[t] - val;
}

__global__ __launch_bounds__(256) void scan_final(int* __restrict__ v,
                                                  const int* __restrict__ bsums, int n) {
    __shared__ int sh[256];
    int t = threadIdx.x;
    int i = blockIdx.x * 256 + t;
    int val = (i < n) ? v[i] : 0;
    sh[t] = val;
    __syncthreads();
    for (int off = 1; off < 256; off <<= 1) {
        int x = (t >= off) ? sh[t - off] : 0;
        __syncthreads();
        sh[t] += x;
        __syncthreads();
    }
    int excl = sh[t] - val + bsums[blockIdx.x];
    if (i < n) v[i] = excl;
    if (i == n - 1) v[n] = excl + val;
}

__global__ __launch_bounds__(256) void fill_kernel(const int* __restrict__ src,
                                                   const int* __restrict__ dst,
                                                   const int* __restrict__ row_start,
                                                   int* __restrict__ cursor,
                                                   int* __restrict__ csr_src, int E) {
    int e = blockIdx.x * 256 + threadIdx.x;
    if (e < E) {
        int d = dst[e];
        int pos = row_start[d] + atomicAdd(&cursor[d], 1);
        csr_src[pos] = src[e];
    }
}

// f32 [n8*8] -> bf16, 8 elems/thread
__global__ __launch_bounds__(256) void convert_bf16(const float* __restrict__ in,
                                                    u16* __restrict__ out, int n8) {
    int i = blockIdx.x * 256 + threadIdx.x;
    if (i >= n8) return;
    const float4* p = (const float4*)in + (size_t)i * 2;
    float4 v0 = p[0], v1 = p[1];
    uint4 o;
    o.x = (u32)f32_to_bf16(v0.x) | ((u32)f32_to_bf16(v0.y) << 16);
    o.y = (u32)f32_to_bf16(v0.z) | ((u32)f32_to_bf16(v0.w) << 16);
    o.z = (u32)f32_to_bf16(v1.x) | ((u32)f32_to_bf16(v1.y) << 16);
    o.w = (u32)f32_to_bf16(v1.z) | ((u32)f32_to_bf16(v1.w) << 16);
    ((uint4*)out)[i] = o;
}

// W [K][N] f32 -> WT [N][K] bf16, 32x32 tiles
__global__ __launch_bounds__(256) void transpose_w(const float* __restrict__ W,
                                                   u16* __restrict__ WT,
                                                   int K, int N) {
    __shared__ float t[32][33];
    int n0 = blockIdx.x * 32, k0 = blockIdx.y * 32;
    int c = threadIdx.x & 31, r0 = threadIdx.x >> 5;
    for (int r = r0; r < 32; r += 8)
        t[r][c] = W[(size_t)(k0 + r) * N + n0 + c];
    __syncthreads();
    for (int r = r0; r < 32; r += 8)
        WT[(size_t)(n0 + r) * K + k0 + c] = f32_to_bf16(t[c][r]);
}

// C = A @ BT' (BT stored [N][512], k-contig), K=512, bf16 out.
// 256x256 tile, 512 threads, 8-phase-style lockstep schedule (see header).
// Output split: cols < split -> Cl (row stride split), else Cr.
__global__ __launch_bounds__(512, 2) void gemm256(
    const u16* __restrict__ A, const u16* __restrict__ BT,
    u16* __restrict__ Cl, u16* __restrict__ Cr,
    int M, int split, int nStrips, int nCols) {
    extern __shared__ u16 lds[];   // 131072 B: 2 slots x (A 16384 + B 16384) u16

    const int grp = 8 * nCols;
    int b = blockIdx.x;
    int strip = (b / grp) * 8 + (b & 7);   // col-tiles of a strip share b%8 -> XCD
    int colt = (b % grp) >> 3;
    if (strip >= nStrips) return;
    const int row0 = strip * 256, col0 = colt * 256;

    const int t = threadIdx.x;
    const int w = t >> 6, lane = t & 63;
    const int arow = (w >> 2) * 128;       // wave M-half base row
    const int bcol = (w & 3) * 64;         // wave N-quarter base col
    const int l15 = lane & 15, kq = lane >> 4;
    const int rchunk = (kq ^ ((l15 >> 1) & 3)) * 8;  // swizzled read chunk (u16)

    floatx4 acc[8][4];
#pragma unroll
    for (int i = 0; i < 8; ++i)
#pragma unroll
        for (int j = 0; j < 4; ++j) acc[i][j] = floatx4{0.f, 0.f, 0.f, 0.f};

    // Staging rounds: round i covers 16-row units: wave w -> rows
    // rb = (w&3)*16 + (i&1)*64 + (w>>2)*128, plane = i>>1 (kk-half).
    // HW lane-linear dest: lane -> row rb+(lane>>2), chunk lane&3.
    // Source pre-swizzle: chunk (lane&3)^((lane>>3)&3)  [rule-21 involution].
    auto stA = [&](int kt2, int i) {
        const int rb = (w & 3) * 16 + (i & 1) * 64 + (w >> 2) * 128;
        const int plane = i >> 1;
        const size_t src = (size_t)min(row0 + rb + (lane >> 2), M - 1) * 512
                         + kt2 * 64 + plane * 32
                         + (((lane & 3) ^ ((lane >> 3) & 3)) * 8);
        const int dst = (kt2 & 1) * 32768 + plane * 8192 + rb * 32;
        ASYNC16(A + src, &lds[dst]);
    };
    auto stB = [&](int kt2, int i) {
        const int rb = (w & 3) * 16 + (i & 1) * 64 + (w >> 2) * 128;
        const int plane = i >> 1;
        const size_t src = (size_t)(col0 + rb + (lane >> 2)) * 512
                         + kt2 * 64 + plane * 32
                         + (((lane & 3) ^ ((lane >> 3) & 3)) * 8);
        const int dst = (kt2 & 1) * 32768 + 16384 + plane * 8192 + rb * 32;
        ASYNC16(BT + src, &lds[dst]);
    };

    // Prologue: kt0 fully (8 rounds) + kt1 A rounds 0,2; wait all but last 2.
    stA(0, 0); stA(0, 1); stA(0, 2); stA(0, 3);
    stB(0, 0); stB(0, 1); stB(0, 2); stB(0, 3);
    stA(1, 0); stA(1, 2);
    asm volatile("s_waitcnt vmcnt(2)" ::: "memory");
    __builtin_amdgcn_s_barrier();

    for (int kt = 0; kt < 8; ++kt) {
        const int sA = (kt & 1) * 32768;
        const int sB = sA + 16384;

        // B-frags for the whole K-tile (held in regs across phases)
        short8 bfr[4][2];
#pragma unroll
        for (int nt = 0; nt < 4; ++nt)
#pragma unroll
            for (int j = 0; j < 2; ++j)
                bfr[nt][j] = *(const short8*)
                    &lds[sB + j * 8192 + (bcol + nt * 16 + l15) * 32 + rchunk];

#pragma unroll
        for (int q = 0; q < 4; ++q) {
            // --- stage (2 rounds/phase, death-ledger in header) ---
            if (q == 0)      { if (kt + 1 < 8) { stA(kt + 1, 1); stA(kt + 1, 3); } }
            else if (q == 1) { if (kt + 1 < 8) { stB(kt + 1, 0); stB(kt + 1, 2); } }
            else if (q == 2) { if (kt + 1 < 8) { stB(kt + 1, 1); stB(kt + 1, 3); } }
            else             { if (kt + 2 < 8) { stA(kt + 2, 0); stA(kt + 2, 2); } }

            // --- A-frags for this quadrant (rows [q*32,(q+1)*32) of wave) ---
            short8 afr[2][2];
#pragma unroll
            for (int m2 = 0; m2 < 2; ++m2)
#pragma unroll
                for (int j = 0; j < 2; ++j)
                    afr[m2][j] = *(const short8*)
                        &lds[sA + j * 8192
                             + (arow + (q * 2 + m2) * 16 + l15) * 32 + rchunk];

            // --- 16 MFMA (swapped operands: D = C^T) ---
            __builtin_amdgcn_s_setprio(1);
#pragma unroll
            for (int m2 = 0; m2 < 2; ++m2)
#pragma unroll
                for (int nt = 0; nt < 4; ++nt)
#pragma unroll
                    for (int j = 0; j < 2; ++j)
                        acc[q * 2 + m2][nt] = __builtin_amdgcn_mfma_f32_16x16x32_bf16(
                            bfr[nt][j], afr[m2][j], acc[q * 2 + m2][nt], 0, 0, 0);
            __builtin_amdgcn_s_setprio(0);

            if (q < 3) {
                __builtin_amdgcn_s_barrier();          // phase lockstep (no drain)
            } else if (kt < 7) {
                // K-tile boundary: kt+1 must be landed; ph3's 2 rounds may fly.
                if (kt + 2 < 8) asm volatile("s_waitcnt vmcnt(2)" ::: "memory");
                else            asm volatile("s_waitcnt vmcnt(0)" ::: "memory");
                __builtin_amdgcn_s_barrier();
            }
        }
    }

    // Epilogue (C^T regs): row = row0+arow+mt*16+l15, col = col0+bcol+nt*16+kq*4
#pragma unroll
    for (int mt = 0; mt < 8; ++mt) {
        int row = row0 + arow + mt * 16 + l15;
        if (row >= M) continue;
#pragma unroll
        for (int nt = 0; nt < 4; ++nt) {
            int c0 = col0 + bcol + nt * 16 + kq * 4;
            u16* __restrict__ Cbase = (c0 < split) ? Cl : Cr;
            int cadj = (c0 < split) ? c0 : (c0 - split);
            uint2 o;
            o.x = (u32)f32_to_bf16(acc[mt][nt][0]) |
                  ((u32)f32_to_bf16(acc[mt][nt][1]) << 16);
            o.y = (u32)f32_to_bf16(acc[mt][nt][2]) |
                  ((u32)f32_to_bf16(acc[mt][nt][3]) << 16);
            *(uint2*)(Cbase + (size_t)row * split + cadj) = o;
        }
    }
}

__device__ __forceinline__ void acc8(float* a, uint4 v) {
    a[0] += bf16_to_f32(v.x & 0xffffu); a[1] += bf16_to_f32(v.x >> 16);
    a[2] += bf16_to_f32(v.y & 0xffffu); a[3] += bf16_to_f32(v.y >> 16);
    a[4] += bf16_to_f32(v.z & 0xffffu); a[5] += bf16_to_f32(v.z >> 16);
    a[6] += bf16_to_f32(v.w & 0xffffu); a[7] += bf16_to_f32(v.w >> 16);
}

// h[node] = relu(mean(Yl[src]) + Yr[node] + bias), D=512 bf16.
// One wave per node; lane covers 8 cols (uint4). Neighbor loop 4-deep.
__global__ __launch_bounds__(256) void gather_add_relu512(
    const u16* __restrict__ Yl, const u16* __restrict__ Yr,
    const float* __restrict__ bias,
    const int* __restrict__ row_start, const int* __restrict__ csr_src,
    u16* __restrict__ h, int M) {
    int node = (blockIdx.x * 256 + threadIdx.x) >> 6;
    int lane = threadIdx.x & 63;
    if (node >= M) return;
    int beg = row_start[node], end = row_start[node + 1];
    float a[8] = {0.f, 0.f, 0.f, 0.f, 0.f, 0.f, 0.f, 0.f};
    for (int c = beg; c < end; c += 64) {
        int nb = min(64, end - c);
        int eid = (lane < nb) ? csr_src[c + lane] : 0;
        int i = 0;
        for (; i + 4 <= nb; i += 4) {
            int s0 = __shfl(eid, i);
            int s1 = __shfl(eid, i + 1);
            int s2 = __shfl(eid, i + 2);
            int s3 = __shfl(eid, i + 3);
            uint4 v0 = ((const uint4*)(Yl + (size_t)s0 * 512))[lane];
            uint4 v1 = ((const uint4*)(Yl + (size_t)s1 * 512))[lane];
            uint4 v2 = ((const uint4*)(Yl + (size_t)s2 * 512))[lane];
            uint4 v3 = ((const uint4*)(Yl + (size_t)s3 * 512))[lane];
            acc8(a, v0); acc8(a, v1); acc8(a, v2); acc8(a, v3);
        }
        for (; i < nb; ++i) {
            int s = __shfl(eid, i);
            uint4 v = ((const uint4*)(Yl + (size_t)s * 512))[lane];
            acc8(a, v);
        }
    }
    float inv = 1.0f / fmaxf((float)(end - beg), 1.0f);
    uint4 yr = ((const uint4*)(Yr + (size_t)node * 512))[lane];
    float4 b0 = ((const float4*)bias)[lane * 2];
    float4 b1 = ((const float4*)bias)[lane * 2 + 1];
    float v0 = fmaxf(a[0] * inv + bf16_to_f32(yr.x & 0xffffu) + b0.x, 0.f);
    float v1 = fmaxf(a[1] * inv + bf16_to_f32(yr.x >> 16)     + b0.y, 0.f);
    float v2 = fmaxf(a[2] * inv + bf16_to_f32(yr.y & 0xffffu) + b0.z, 0.f);
    float v3 = fmaxf(a[3] * inv + bf16_to_f32(yr.y >> 16)     + b0.w, 0.f);
    float v4 = fmaxf(a[4] * inv + bf16_to_f32(yr.z & 0xffffu) + b1.x, 0.f);
    float v5 = fmaxf(a[5] * inv + bf16_to_f32(yr.z >> 16)     + b1.y, 0.f);
    float v6 = fmaxf(a[6] * inv + bf16_to_f32(yr.w & 0xffffu) + b1.z, 0.f);
    float v7 = fmaxf(a[7] * inv + bf16_to_f32(yr.w >> 16)     + b1.w, 0.f);
    uint4 o;
    o.x = (u32)f32_to_bf16(v0) | ((u32)f32_to_bf16(v1) << 16);
    o.y = (u32)f32_to_bf16(v2) | ((u32)f32_to_bf16(v3) << 16);
    o.z = (u32)f32_to_bf16(v4) | ((u32)f32_to_bf16(v5) << 16);
    o.w = (u32)f32_to_bf16(v6) | ((u32)f32_to_bf16(v7) << 16);
    ((uint4*)(h + (size_t)node * 512))[lane] = o;
}

// out[node] = log_softmax(mean(Yl[src]) + Yr[node] + bias), D=128, f32 out.
// 16 lanes per node (4 nodes/wave); lane covers 8 cols. Neighbor loop 4-deep.
__global__ __launch_bounds__(256) void gather_add_lsm128(
    const u16* __restrict__ Yl, const u16* __restrict__ Yr,
    const float* __restrict__ bias,
    const int* __restrict__ row_start, const int* __restrict__ csr_src,
    float* __restrict__ out, int M) {
    int node = blockIdx.x * 16 + (threadIdx.x >> 4);
    int lane = threadIdx.x & 63;
    int li = lane & 15;
    int gbase = lane & 48;      // group base lane within wave
    if (node >= M) return;
    int beg = row_start[node], end = row_start[node + 1];
    float a[8] = {0.f, 0.f, 0.f, 0.f, 0.f, 0.f, 0.f, 0.f};
    for (int c = beg; c < end; c += 16) {
        int nb = min(16, end - c);
        int eid = (li < nb) ? csr_src[c + li] : 0;
        int i = 0;
        for (; i + 4 <= nb; i += 4) {
            int s0 = __shfl(eid, gbase + i);
            int s1 = __shfl(eid, gbase + i + 1);
            int s2 = __shfl(eid, gbase + i + 2);
            int s3 = __shfl(eid, gbase + i + 3);
            uint4 v0 = ((const uint4*)(Yl + (size_t)s0 * 128))[li];
            uint4 v1 = ((const uint4*)(Yl + (size_t)s1 * 128))[li];
            uint4 v2 = ((const uint4*)(Yl + (size_t)s2 * 128))[li];
            uint4 v3 = ((const uint4*)(Yl + (size_t)s3 * 128))[li];
            acc8(a, v0); acc8(a, v1); acc8(a, v2); acc8(a, v3);
        }
        for (; i < nb; ++i) {
            int s = __shfl(eid, gbase + i);
            uint4 v = ((const uint4*)(Yl + (size_t)s * 128))[li];
            acc8(a, v);
        }
    }
    float inv = 1.0f / fmaxf((float)(end - beg), 1.0f);
    uint4 yr = ((const uint4*)(Yr + (size_t)node * 128))[li];
    float4 b0 = ((const float4*)bias)[li * 2];
    float4 b1 = ((const float4*)bias)[li * 2 + 1];
    float v[8];
    v[0] = a[0] * inv + bf16_to_f32(yr.x & 0xffffu) + b0.x;
    v[1] = a[1] * inv + bf16_to_f32(yr.x >> 16)     + b0.y;
    v[2] = a[2] * inv + bf16_to_f32(yr.y & 0xffffu) + b0.z;
    v[3] = a[3] * inv + bf16_to_f32(yr.y >> 16)     + b0.w;
    v[4] = a[4] * inv + bf16_to_f32(yr.z & 0xffffu) + b1.x;
    v[5] = a[5] * inv + bf16_to_f32(yr.z >> 16)     + b1.y;
    v[6] = a[6] * inv + bf16_to_f32(yr.w & 0xffffu) + b1.z;
    v[7] = a[7] * inv + bf16_to_f32(yr.w >> 16)     + b1.w;
    float m = v[0];
#pragma unroll
    for (int j = 1; j < 8; ++j) m = fmaxf(m, v[j]);
#pragma unroll
    for (int off = 1; off < 16; off <<= 1) m = fmaxf(m, __shfl_xor(m, off));
    float s = 0.f;
#pragma unroll
    for (int j = 0; j < 8; ++j) s += expf(v[j] - m);
#pragma unroll
    for (int off = 1; off < 16; off <<= 1) s += __shfl_xor(s, off);
    float ls = m + logf(s);
    float* p = out + (size_t)node * 128 + li * 8;
    *(float4*)p       = make_float4(v[0] - ls, v[1] - ls, v[2] - ls, v[3] - ls);
    *(float4*)(p + 4) = make_float4(v[4] - ls, v[5] - ls, v[6] - ls, v[7] - ls);
}

extern "C" void kernel_launch(void* const* d_in, const int* in_sizes, int n_in,
                              void* d_out, int out_size, void* d_ws, size_t ws_size,
                              hipStream_t stream) {
    const float* x    = (const float*)d_in[0];
    const int*   ei   = (const int*)d_in[1];
    const float* W1_l = (const float*)d_in[2];
    const float* b1   = (const float*)d_in[3];
    const float* W1_r = (const float*)d_in[4];
    const float* W2_l = (const float*)d_in[5];
    const float* b2   = (const float*)d_in[6];
    const float* W2_r = (const float*)d_in[7];
    const float* W3_l = (const float*)d_in[8];
    const float* b3   = (const float*)d_in[9];
    const float* W3_r = (const float*)d_in[10];
    float* out = (float*)d_out;

    const int* src = ei;
    const int* dst = ei + N_EDGES;

    // Workspace layout (bytes from base):
    char* base = (char*)d_ws;
    int* row_start = (int*)(base);                    // 50052 ints
    int* cursor    = (int*)(base + 200208);           // 50052 ints
    int* bsums     = (int*)(base + 400416);           // 512 ints
    int* csr_src   = (int*)(base + 402464);           // 400000 ints -> end 2002464
    u16* xb  = (u16*)(base + 2002464);                // [M][512] bf16
    u16* h1b = (u16*)(base + 53202464);               // [M][512]
    u16* h2b = (u16*)(base + 104402464);              // [M][512]
    u16* Yl  = (u16*)(base + 155602464);              // [M][512] (layer3: [M][128])
    u16* Yr  = (u16*)(base + 206802464);              // [M][512] (layer3: [M][128])
    u16* w1T = (u16*)(base + 258002464);              // [1024][512]
    u16* w2T = (u16*)(base + 259051040);              // [1024][512]
    u16* w3T = (u16*)(base + 260099616);              // [256][512] -> end 260361760

    const int E = N_EDGES, M = N_NODES;
    const int nblk = (M + 255) / 256;

    // 128KB dynamic LDS opt-in (idempotent; host-side, not a stream op)
    static int attrSet = 0;
    if (!attrSet) {
        hipFuncSetAttribute((const void*)gemm256,
                            hipFuncAttributeMaxDynamicSharedMemorySize, 131072);
        attrSet = 1;
    }

    // ---- CSR build ----
    zero4_kernel<<<(25154 + 255) / 256, 256, 0, stream>>>((float4*)d_ws, 25154);
    hist_kernel<<<(E + 255) / 256, 256, 0, stream>>>(dst, row_start, E);
    scan_reduce<<<nblk, 256, 0, stream>>>(row_start, bsums, M);
    scan_sums<<<1, 256, 0, stream>>>(bsums, nblk);
    scan_final<<<nblk, 256, 0, stream>>>(row_start, bsums, M);
    fill_kernel<<<(E + 255) / 256, 256, 0, stream>>>(src, dst, row_start, cursor,
                                                     csr_src, E);

    // ---- conversions: x -> bf16; weights -> WT [N][K] bf16, l/r concat ----
    convert_bf16<<<(3200000 + 255) / 256, 256, 0, stream>>>(x, xb, 3200000);
    transpose_w<<<dim3(16, 16), 256, 0, stream>>>(W1_l, w1T, 512, 512);
    transpose_w<<<dim3(16, 16), 256, 0, stream>>>(W1_r, w1T + 512 * 512, 512, 512);
    transpose_w<<<dim3(16, 16), 256, 0, stream>>>(W2_l, w2T, 512, 512);
    transpose_w<<<dim3(16, 16), 256, 0, stream>>>(W2_r, w2T + 512 * 512, 512, 512);
    transpose_w<<<dim3(4, 16), 256, 0, stream>>>(W3_l, w3T, 512, 128);
    transpose_w<<<dim3(4, 16), 256, 0, stream>>>(W3_r, w3T + 128 * 512, 512, 128);

    const int nStrips = (M + 255) / 256;                 // 196 (256-row strips)
    const int grid12 = ((nStrips + 7) / 8) * 8 * 4;      // 800 (nCols=4, N=1024)
    const int grid3  = ((nStrips + 7) / 8) * 8 * 1;      // 200 (nCols=1, N=256)
    const int gblocks = (M * 64 + 255) / 256;            // wave/node
    const int g16blocks = (M + 15) / 16;                 // 16 lanes/node

    // ---- layer 1: Y = x@[W1_l|W1_r]; h1 = relu(gather(Yl)+Yr+b1) ----
    gemm256<<<grid12, 512, 131072, stream>>>(xb, w1T, Yl, Yr, M, 512, nStrips, 4);
    gather_add_relu512<<<gblocks, 256, 0, stream>>>(Yl, Yr, b1, row_start,
                                                    csr_src, h1b, M);
    // ---- layer 2 ----
    gemm256<<<grid12, 512, 131072, stream>>>(h1b, w2T, Yl, Yr, M, 512, nStrips, 4);
    gather_add_relu512<<<gblocks, 256, 0, stream>>>(Yl, Yr, b2, row_start,
                                                    csr_src, h2b, M);
    // ---- layer 3: Y3 = h2@[W3_l|W3_r]; out = lsm(gather(Y3l)+Y3r+b3) ----
    gemm256<<<grid3, 512, 131072, stream>>>(h2b, w3T, Yl, Yr, M, 128, nStrips, 1);
    gather_add_lsm128<<<g16blocks, 256, 0, stream>>>(Yl, Yr, b3, row_start,
                                                     csr_src, out, M);
}

// Round 11
// 591.136 us; speedup vs baseline: 1.2311x; 1.0556x over previous
//
#include <hip/hip_runtime.h>
#include <hip/hip_bf16.h>

// GraphSAGE 3-layer, N=50000 nodes, E=400000 edges, dims 512->512->512->128.
// Round 18: R10 (624us, best) + LDS-REPACK EPILOGUE in gemm256.
// Rationale: 8 GEMM variants (R1-R10) all ~107us; the two best (128x128
// 2-phase, 256x256 counted-vmcnt lockstep) agree within 1% and both fit
// dur = FETCH/6.3TB/s + WRITE/1.0TB/s exactly -> effective WRITE path at
// ~1.0 TB/s. The one never-varied pattern: uint2 8-B/lane scatter stores
// (16 rows x 32-B fragments per instruction, 1-KB stride). R6's 22% write
// amplification (122MB WRITE for 100MB C) corroborates partial-line cost.
// Fix: after K-loop (LDS dead, vmcnt drained), scatter acc->LDS bf16 tile
// [256][32 chunks x 16B] with chunk-XOR swizzle (c^=row&31; write 2-way=
// free, read minimal), then 16 rounds of ds_read_b128 + store_dwordx4:
// each wave stores 2 rows x 512 B FULLY CONTIGUOUS per instruction.
// Everything else byte-identical to R10.

#define N_NODES 50000
#define N_EDGES 400000

typedef unsigned short u16;
typedef unsigned int u32;
typedef __attribute__((ext_vector_type(8))) short short8;
typedef __attribute__((ext_vector_type(4))) float floatx4;

#define ASYNC16(g, l)                                                      \
    __builtin_amdgcn_global_load_lds(                                      \
        (const __attribute__((address_space(1))) void*)(g),                \
        (__attribute__((address_space(3))) void*)(l), 16, 0, 0)

__device__ __forceinline__ u16 f32_to_bf16(float f) {
    u32 u = __float_as_uint(f);
    u32 r = 0x7FFFu + ((u >> 16) & 1u);
    return (u16)((u + r) >> 16);
}
__device__ __forceinline__ float bf16_to_f32(u32 lo16) {
    return __uint_as_float(lo16 << 16);
}

__global__ __launch_bounds__(256) void zero4_kernel(float4* __restrict__ p, int n4) {
    int i = blockIdx.x * 256 + threadIdx.x;
    if (i < n4) p[i] = make_float4(0.f, 0.f, 0.f, 0.f);
}

__global__ __launch_bounds__(256) void hist_kernel(const int* __restrict__ dst,
                                                   int* __restrict__ deg, int E) {
    int e = blockIdx.x * 256 + threadIdx.x;
    if (e < E) atomicAdd(&deg[dst[e]], 1);
}

__global__ __launch_bounds__(256) void scan_reduce(const int* __restrict__ v,
                                                   int* __restrict__ bsums, int n) {
    __shared__ int sh[256];
    int i = blockIdx.x * 256 + threadIdx.x;
    sh[threadIdx.x] = (i < n) ? v[i] : 0;
    __syncthreads();
    for (int off = 128; off > 0; off >>= 1) {
        if (threadIdx.x < off) sh[threadIdx.x] += sh[threadIdx.x + off];
        __syncthreads();
    }
    if (threadIdx.x == 0) bsums[blockIdx.x] = sh[0];
}

__global__ __launch_bounds__(256) void scan_sums(int* __restrict__ bsums, int nb) {
    __shared__ int sh[256];
    int t = threadIdx.x;
    int val = (t < nb) ? bsums[t] : 0;
    sh[t] = val;
    __syncthreads();
    for (int off = 1; off < 256; off <<= 1) {
        int v = (t >= off) ? sh[t - off] : 0;
        __syncthreads();
        sh[t] += v;
        __syncthreads();
    }
    if (t < nb) bsums[t] = sh[t] - val;
}

__global__ __launch_bounds__(256) void scan_final(int* __restrict__ v,
                                                  const int* __restrict__ bsums, int n) {
    __shared__ int sh[256];
    int t = threadIdx.x;
    int i = blockIdx.x * 256 + t;
    int val = (i < n) ? v[i] : 0;
    sh[t] = val;
    __syncthreads();
    for (int off = 1; off < 256; off <<= 1) {
        int x = (t >= off) ? sh[t - off] : 0;
        __syncthreads();
        sh[t] += x;
        __syncthreads();
    }
    int excl = sh[t] - val + bsums[blockIdx.x];
    if (i < n) v[i] = excl;
    if (i == n - 1) v[n] = excl + val;
}

__global__ __launch_bounds__(256) void fill_kernel(const int* __restrict__ src,
                                                   const int* __restrict__ dst,
                                                   const int* __restrict__ row_start,
                                                   int* __restrict__ cursor,
                                                   int* __restrict__ csr_src, int E) {
    int e = blockIdx.x * 256 + threadIdx.x;
    if (e < E) {
        int d = dst[e];
        int pos = row_start[d] + atomicAdd(&cursor[d], 1);
        csr_src[pos] = src[e];
    }
}

// f32 [n8*8] -> bf16, 8 elems/thread
__global__ __launch_bounds__(256) void convert_bf16(const float* __restrict__ in,
                                                    u16* __restrict__ out, int n8) {
    int i = blockIdx.x * 256 + threadIdx.x;
    if (i >= n8) return;
    const float4* p = (const float4*)in + (size_t)i * 2;
    float4 v0 = p[0], v1 = p[1];
    uint4 o;
    o.x = (u32)f32_to_bf16(v0.x) | ((u32)f32_to_bf16(v0.y) << 16);
    o.y = (u32)f32_to_bf16(v0.z) | ((u32)f32_to_bf16(v0.w) << 16);
    o.z = (u32)f32_to_bf16(v1.x) | ((u32)f32_to_bf16(v1.y) << 16);
    o.w = (u32)f32_to_bf16(v1.z) | ((u32)f32_to_bf16(v1.w) << 16);
    ((uint4*)out)[i] = o;
}

// W [K][N] f32 -> WT [N][K] bf16, 32x32 tiles
__global__ __launch_bounds__(256) void transpose_w(const float* __restrict__ W,
                                                   u16* __restrict__ WT,
                                                   int K, int N) {
    __shared__ float t[32][33];
    int n0 = blockIdx.x * 32, k0 = blockIdx.y * 32;
    int c = threadIdx.x & 31, r0 = threadIdx.x >> 5;
    for (int r = r0; r < 32; r += 8)
        t[r][c] = W[(size_t)(k0 + r) * N + n0 + c];
    __syncthreads();
    for (int r = r0; r < 32; r += 8)
        WT[(size_t)(n0 + r) * K + k0 + c] = f32_to_bf16(t[c][r]);
}

// C = A @ BT' (BT stored [N][512], k-contig), K=512, bf16 out.
// 256x256 tile, 512 threads, 4-phase lockstep schedule (R10) +
// LDS-repack epilogue for fully-coalesced C stores.
__global__ __launch_bounds__(512, 2) void gemm256(
    const u16* __restrict__ A, const u16* __restrict__ BT,
    u16* __restrict__ Cl, u16* __restrict__ Cr,
    int M, int split, int nStrips, int nCols) {
    extern __shared__ u16 lds[];   // 131072 B: 2 slots x (A 16384 + B 16384) u16

    const int grp = 8 * nCols;
    int b = blockIdx.x;
    int strip = (b / grp) * 8 + (b & 7);   // col-tiles of a strip share b%8 -> XCD
    int colt = (b % grp) >> 3;
    if (strip >= nStrips) return;
    const int row0 = strip * 256, col0 = colt * 256;

    const int t = threadIdx.x;
    const int w = t >> 6, lane = t & 63;
    const int arow = (w >> 2) * 128;       // wave M-half base row
    const int bcol = (w & 3) * 64;         // wave N-quarter base col
    const int l15 = lane & 15, kq = lane >> 4;
    const int rchunk = (kq ^ ((l15 >> 1) & 3)) * 8;  // swizzled read chunk (u16)

    floatx4 acc[8][4];
#pragma unroll
    for (int i = 0; i < 8; ++i)
#pragma unroll
        for (int j = 0; j < 4; ++j) acc[i][j] = floatx4{0.f, 0.f, 0.f, 0.f};

    auto stA = [&](int kt2, int i) {
        const int rb = (w & 3) * 16 + (i & 1) * 64 + (w >> 2) * 128;
        const int plane = i >> 1;
        const size_t src = (size_t)min(row0 + rb + (lane >> 2), M - 1) * 512
                         + kt2 * 64 + plane * 32
                         + (((lane & 3) ^ ((lane >> 3) & 3)) * 8);
        const int dst = (kt2 & 1) * 32768 + plane * 8192 + rb * 32;
        ASYNC16(A + src, &lds[dst]);
    };
    auto stB = [&](int kt2, int i) {
        const int rb = (w & 3) * 16 + (i & 1) * 64 + (w >> 2) * 128;
        const int plane = i >> 1;
        const size_t src = (size_t)(col0 + rb + (lane >> 2)) * 512
                         + kt2 * 64 + plane * 32
                         + (((lane & 3) ^ ((lane >> 3) & 3)) * 8);
        const int dst = (kt2 & 1) * 32768 + 16384 + plane * 8192 + rb * 32;
        ASYNC16(BT + src, &lds[dst]);
    };

    // Prologue: kt0 fully (8 rounds) + kt1 A rounds 0,2; wait all but last 2.
    stA(0, 0); stA(0, 1); stA(0, 2); stA(0, 3);
    stB(0, 0); stB(0, 1); stB(0, 2); stB(0, 3);
    stA(1, 0); stA(1, 2);
    asm volatile("s_waitcnt vmcnt(2)" ::: "memory");
    __builtin_amdgcn_s_barrier();

    for (int kt = 0; kt < 8; ++kt) {
        const int sA = (kt & 1) * 32768;
        const int sB = sA + 16384;

        short8 bfr[4][2];
#pragma unroll
        for (int nt = 0; nt < 4; ++nt)
#pragma unroll
            for (int j = 0; j < 2; ++j)
                bfr[nt][j] = *(const short8*)
                    &lds[sB + j * 8192 + (bcol + nt * 16 + l15) * 32 + rchunk];

#pragma unroll
        for (int q = 0; q < 4; ++q) {
            if (q == 0)      { if (kt + 1 < 8) { stA(kt + 1, 1); stA(kt + 1, 3); } }
            else if (q == 1) { if (kt + 1 < 8) { stB(kt + 1, 0); stB(kt + 1, 2); } }
            else if (q == 2) { if (kt + 1 < 8) { stB(kt + 1, 1); stB(kt + 1, 3); } }
            else             { if (kt + 2 < 8) { stA(kt + 2, 0); stA(kt + 2, 2); } }

            short8 afr[2][2];
#pragma unroll
            for (int m2 = 0; m2 < 2; ++m2)
#pragma unroll
                for (int j = 0; j < 2; ++j)
                    afr[m2][j] = *(const short8*)
                        &lds[sA + j * 8192
                             + (arow + (q * 2 + m2) * 16 + l15) * 32 + rchunk];

            __builtin_amdgcn_s_setprio(1);
#pragma unroll
            for (int m2 = 0; m2 < 2; ++m2)
#pragma unroll
                for (int nt = 0; nt < 4; ++nt)
#pragma unroll
                    for (int j = 0; j < 2; ++j)
                        acc[q * 2 + m2][nt] = __builtin_amdgcn_mfma_f32_16x16x32_bf16(
                            bfr[nt][j], afr[m2][j], acc[q * 2 + m2][nt], 0, 0, 0);
            __builtin_amdgcn_s_setprio(0);

            if (q < 3) {
                __builtin_amdgcn_s_barrier();          // phase lockstep (no drain)
            } else if (kt < 7) {
                if (kt + 2 < 8) asm volatile("s_waitcnt vmcnt(2)" ::: "memory");
                else            asm volatile("s_waitcnt vmcnt(0)" ::: "memory");
                __builtin_amdgcn_s_barrier();
            }
        }
    }

    // ---- LDS-repack epilogue ----
    // LDS is dead (all staging drained by kt=6 boundary vmcnt(0); kt=7 reads
    // landed in regs). Reuse all 128KB as a [256 rows][32 chunks x 16B] bf16
    // tile, chunk-XOR-swizzled: physical chunk = c ^ (row & 31).
    asm volatile("s_waitcnt vmcnt(0)" ::: "memory");
    __builtin_amdgcn_s_barrier();

    // Phase 1: scatter acc (C^T regs) -> LDS tile. Element: tile row =
    // arow+mt*16+l15, tile col(u16) = bcol+nt*16+kq*4 (+0..3 within uint2x2).
#pragma unroll
    for (int mt = 0; mt < 8; ++mt) {
        const int trow = arow + mt * 16 + l15;
#pragma unroll
        for (int nt = 0; nt < 4; ++nt) {
            const int tcol = bcol + nt * 16 + kq * 4;
            const int c = tcol >> 3;                    // 16B chunk 0..31
            const int ph = (c ^ (trow & 31)) << 3;      // swizzled chunk base
            uint2 o;
            o.x = (u32)f32_to_bf16(acc[mt][nt][0]) |
                  ((u32)f32_to_bf16(acc[mt][nt][1]) << 16);
            o.y = (u32)f32_to_bf16(acc[mt][nt][2]) |
                  ((u32)f32_to_bf16(acc[mt][nt][3]) << 16);
            *(uint2*)&lds[trow * 256 + ph + (tcol & 7)] = o;
        }
    }
    __builtin_amdgcn_s_barrier();

    // Phase 2: contiguous drain. Thread t covers row i*16 + (t>>5), logical
    // chunk t&31. Per wave-instruction: 2 rows x 512 B fully contiguous.
    const int rloc = t >> 5;        // 0..15
    const int clog = t & 31;
#pragma unroll
    for (int i = 0; i < 16; ++i) {
        const int trow = i * 16 + rloc;
        const int row = row0 + trow;
        const uint4 v = *(const uint4*)&lds[trow * 256 + ((clog ^ (trow & 31)) << 3)];
        if (row < M) {
            const int gc = col0 + clog * 8;             // global col (u16)
            u16* __restrict__ Cbase = (gc < split) ? Cl : Cr;
            const int cadj = (gc < split) ? gc : (gc - split);
            *(uint4*)(Cbase + (size_t)row * split + cadj) = v;
        }
    }
}

__device__ __forceinline__ void acc8(float* a, uint4 v) {
    a[0] += bf16_to_f32(v.x & 0xffffu); a[1] += bf16_to_f32(v.x >> 16);
    a[2] += bf16_to_f32(v.y & 0xffffu); a[3] += bf16_to_f32(v.y >> 16);
    a[4] += bf16_to_f32(v.z & 0xffffu); a[5] += bf16_to_f32(v.z >> 16);
    a[6] += bf16_to_f32(v.w & 0xffffu); a[7] += bf16_to_f32(v.w >> 16);
}

// h[node] = relu(mean(Yl[src]) + Yr[node] + bias), D=512 bf16.
// One wave per node; lane covers 8 cols (uint4). Neighbor loop 4-deep.
__global__ __launch_bounds__(256) void gather_add_relu512(
    const u16* __restrict__ Yl, const u16* __restrict__ Yr,
    const float* __restrict__ bias,
    const int* __restrict__ row_start, const int* __restrict__ csr_src,
    u16* __restrict__ h, int M) {
    int node = (blockIdx.x * 256 + threadIdx.x) >> 6;
    int lane = threadIdx.x & 63;
    if (node >= M) return;
    int beg = row_start[node], end = row_start[node + 1];
    float a[8] = {0.f, 0.f, 0.f, 0.f, 0.f, 0.f, 0.f, 0.f};
    for (int c = beg; c < end; c += 64) {
        int nb = min(64, end - c);
        int eid = (lane < nb) ? csr_src[c + lane] : 0;
        int i = 0;
        for (; i + 4 <= nb; i += 4) {
            int s0 = __shfl(eid, i);
            int s1 = __shfl(eid, i + 1);
            int s2 = __shfl(eid, i + 2);
            int s3 = __shfl(eid, i + 3);
            uint4 v0 = ((const uint4*)(Yl + (size_t)s0 * 512))[lane];
            uint4 v1 = ((const uint4*)(Yl + (size_t)s1 * 512))[lane];
            uint4 v2 = ((const uint4*)(Yl + (size_t)s2 * 512))[lane];
            uint4 v3 = ((const uint4*)(Yl + (size_t)s3 * 512))[lane];
            acc8(a, v0); acc8(a, v1); acc8(a, v2); acc8(a, v3);
        }
        for (; i < nb; ++i) {
            int s = __shfl(eid, i);
            uint4 v = ((const uint4*)(Yl + (size_t)s * 512))[lane];
            acc8(a, v);
        }
    }
    float inv = 1.0f / fmaxf((float)(end - beg), 1.0f);
    uint4 yr = ((const uint4*)(Yr + (size_t)node * 512))[lane];
    float4 b0 = ((const float4*)bias)[lane * 2];
    float4 b1 = ((const float4*)bias)[lane * 2 + 1];
    float v0 = fmaxf(a[0] * inv + bf16_to_f32(yr.x & 0xffffu) + b0.x, 0.f);
    float v1 = fmaxf(a[1] * inv + bf16_to_f32(yr.x >> 16)     + b0.y, 0.f);
    float v2 = fmaxf(a[2] * inv + bf16_to_f32(yr.y & 0xffffu) + b0.z, 0.f);
    float v3 = fmaxf(a[3] * inv + bf16_to_f32(yr.y >> 16)     + b0.w, 0.f);
    float v4 = fmaxf(a[4] * inv + bf16_to_f32(yr.z & 0xffffu) + b1.x, 0.f);
    float v5 = fmaxf(a[5] * inv + bf16_to_f32(yr.z >> 16)     + b1.y, 0.f);
    float v6 = fmaxf(a[6] * inv + bf16_to_f32(yr.w & 0xffffu) + b1.z, 0.f);
    float v7 = fmaxf(a[7] * inv + bf16_to_f32(yr.w >> 16)     + b1.w, 0.f);
    uint4 o;
    o.x = (u32)f32_to_bf16(v0) | ((u32)f32_to_bf16(v1) << 16);
    o.y = (u32)f32_to_bf16(v2) | ((u32)f32_to_bf16(v3) << 16);
    o.z = (u32)f32_to_bf16(v4) | ((u32)f32_to_bf16(v5) << 16);
    o.w = (u32)f32_to_bf16(v6) | ((u32)f32_to_bf16(v7) << 16);
    ((uint4*)(h + (size_t)node * 512))[lane] = o;
}

// out[node] = log_softmax(mean(Yl[src]) + Yr[node] + bias), D=128, f32 out.
// 16 lanes per node (4 nodes/wave); lane covers 8 cols. Neighbor loop 4-deep.
__global__ __launch_bounds__(256) void gather_add_lsm128(
    const u16* __restrict__ Yl, const u16* __restrict__ Yr,
    const float* __restrict__ bias,
    const int* __restrict__ row_start, const int* __restrict__ csr_src,
    float* __restrict__ out, int M) {
    int node = blockIdx.x * 16 + (threadIdx.x >> 4);
    int lane = threadIdx.x & 63;
    int li = lane & 15;
    int gbase = lane & 48;      // group base lane within wave
    if (node >= M) return;
    int beg = row_start[node], end = row_start[node + 1];
    float a[8] = {0.f, 0.f, 0.f, 0.f, 0.f, 0.f, 0.f, 0.f};
    for (int c = beg; c < end; c += 16) {
        int nb = min(16, end - c);
        int eid = (li < nb) ? csr_src[c + li] : 0;
        int i = 0;
        for (; i + 4 <= nb; i += 4) {
            int s0 = __shfl(eid, gbase + i);
            int s1 = __shfl(eid, gbase + i + 1);
            int s2 = __shfl(eid, gbase + i + 2);
            int s3 = __shfl(eid, gbase + i + 3);
            uint4 v0 = ((const uint4*)(Yl + (size_t)s0 * 128))[li];
            uint4 v1 = ((const uint4*)(Yl + (size_t)s1 * 128))[li];
            uint4 v2 = ((const uint4*)(Yl + (size_t)s2 * 128))[li];
            uint4 v3 = ((const uint4*)(Yl + (size_t)s3 * 128))[li];
            acc8(a, v0); acc8(a, v1); acc8(a, v2); acc8(a, v3);
        }
        for (; i < nb; ++i) {
            int s = __shfl(eid, gbase + i);
            uint4 v = ((const uint4*)(Yl + (size_t)s * 128))[li];
            acc8(a, v);
        }
    }
    float inv = 1.0f / fmaxf((float)(end - beg), 1.0f);
    uint4 yr = ((const uint4*)(Yr + (size_t)node * 128))[li];
    float4 b0 = ((const float4*)bias)[li * 2];
    float4 b1 = ((const float4*)bias)[li * 2 + 1];
    float v[8];
    v[0] = a[0] * inv + bf16_to_f32(yr.x & 0xffffu) + b0.x;
    v[1] = a[1] * inv + bf16_to_f32(yr.x >> 16)     + b0.y;
    v[2] = a[2] * inv + bf16_to_f32(yr.y & 0xffffu) + b0.z;
    v[3] = a[3] * inv + bf16_to_f32(yr.y >> 16)     + b0.w;
    v[4] = a[4] * inv + bf16_to_f32(yr.z & 0xffffu) + b1.x;
    v[5] = a[5] * inv + bf16_to_f32(yr.z >> 16)     + b1.y;
    v[6] = a[6] * inv + bf16_to_f32(yr.w & 0xffffu) + b1.z;
    v[7] = a[7] * inv + bf16_to_f32(yr.w >> 16)     + b1.w;
    float m = v[0];
#pragma unroll
    for (int j = 1; j < 8; ++j) m = fmaxf(m, v[j]);
#pragma unroll
    for (int off = 1; off < 16; off <<= 1) m = fmaxf(m, __shfl_xor(m, off));
    float s = 0.f;
#pragma unroll
    for (int j = 0; j < 8; ++j) s += expf(v[j] - m);
#pragma unroll
    for (int off = 1; off < 16; off <<= 1) s += __shfl_xor(s, off);
    float ls = m + logf(s);
    float* p = out + (size_t)node * 128 + li * 8;
    *(float4*)p       = make_float4(v[0] - ls, v[1] - ls, v[2] - ls, v[3] - ls);
    *(float4*)(p + 4) = make_float4(v[4] - ls, v[5] - ls, v[6] - ls, v[7] - ls);
}

extern "C" void kernel_launch(void* const* d_in, const int* in_sizes, int n_in,
                              void* d_out, int out_size, void* d_ws, size_t ws_size,
                              hipStream_t stream) {
    const float* x    = (const float*)d_in[0];
    const int*   ei   = (const int*)d_in[1];
    const float* W1_l = (const float*)d_in[2];
    const float* b1   = (const float*)d_in[3];
    const float* W1_r = (const float*)d_in[4];
    const float* W2_l = (const float*)d_in[5];
    const float* b2   = (const float*)d_in[6];
    const float* W2_r = (const float*)d_in[7];
    const float* W3_l = (const float*)d_in[8];
    const float* b3   = (const float*)d_in[9];
    const float* W3_r = (const float*)d_in[10];
    float* out = (float*)d_out;

    const int* src = ei;
    const int* dst = ei + N_EDGES;

    // Workspace layout (bytes from base):
    char* base = (char*)d_ws;
    int* row_start = (int*)(base);                    // 50052 ints
    int* cursor    = (int*)(base + 200208);           // 50052 ints
    int* bsums     = (int*)(base + 400416);           // 512 ints
    int* csr_src   = (int*)(base + 402464);           // 400000 ints -> end 2002464
    u16* xb  = (u16*)(base + 2002464);                // [M][512] bf16
    u16* h1b = (u16*)(base + 53202464);               // [M][512]
    u16* h2b = (u16*)(base + 104402464);              // [M][512]
    u16* Yl  = (u16*)(base + 155602464);              // [M][512] (layer3: [M][128])
    u16* Yr  = (u16*)(base + 206802464);              // [M][512] (layer3: [M][128])
    u16* w1T = (u16*)(base + 258002464);              // [1024][512]
    u16* w2T = (u16*)(base + 259051040);              // [1024][512]
    u16* w3T = (u16*)(base + 260099616);              // [256][512] -> end 260361760

    const int E = N_EDGES, M = N_NODES;
    const int nblk = (M + 255) / 256;

    // 128KB dynamic LDS opt-in (idempotent; host-side, not a stream op)
    static int attrSet = 0;
    if (!attrSet) {
        hipFuncSetAttribute((const void*)gemm256,
                            hipFuncAttributeMaxDynamicSharedMemorySize, 131072);
        attrSet = 1;
    }

    // ---- CSR build ----
    zero4_kernel<<<(25154 + 255) / 256, 256, 0, stream>>>((float4*)d_ws, 25154);
    hist_kernel<<<(E + 255) / 256, 256, 0, stream>>>(dst, row_start, E);
    scan_reduce<<<nblk, 256, 0, stream>>>(row_start, bsums, M);
    scan_sums<<<1, 256, 0, stream>>>(bsums, nblk);
    scan_final<<<nblk, 256, 0, stream>>>(row_start, bsums, M);
    fill_kernel<<<(E + 255) / 256, 256, 0, stream>>>(src, dst, row_start, cursor,
                                                     csr_src, E);

    // ---- conversions: x -> bf16; weights -> WT [N][K] bf16, l/r concat ----
    convert_bf16<<<(3200000 + 255) / 256, 256, 0, stream>>>(x, xb, 3200000);
    transpose_w<<<dim3(16, 16), 256, 0, stream>>>(W1_l, w1T, 512, 512);
    transpose_w<<<dim3(16, 16), 256, 0, stream>>>(W1_r, w1T + 512 * 512, 512, 512);
    transpose_w<<<dim3(16, 16), 256, 0, stream>>>(W2_l, w2T, 512, 512);
    transpose_w<<<dim3(16, 16), 256, 0, stream>>>(W2_r, w2T + 512 * 512, 512, 512);
    transpose_w<<<dim3(4, 16), 256, 0, stream>>>(W3_l, w3T, 512, 128);
    transpose_w<<<dim3(4, 16), 256, 0, stream>>>(W3_r, w3T + 128 * 512, 512, 128);

    const int nStrips = (M + 255) / 256;                 // 196 (256-row strips)
    const int grid12 = ((nStrips + 7) / 8) * 8 * 4;      // 800 (nCols=4, N=1024)
    const int grid3  = ((nStrips + 7) / 8) * 8 * 1;      // 200 (nCols=1, N=256)
    const int gblocks = (M * 64 + 255) / 256;            // wave/node
    const int g16blocks = (M + 15) / 16;                 // 16 lanes/node

    // ---- layer 1: Y = x@[W1_l|W1_r]; h1 = relu(gather(Yl)+Yr+b1) ----
    gemm256<<<grid12, 512, 131072, stream>>>(xb, w1T, Yl, Yr, M, 512, nStrips, 4);
    gather_add_relu512<<<gblocks, 256, 0, stream>>>(Yl, Yr, b1, row_start,
                                                    csr_src, h1b, M);
    // ---- layer 2 ----
    gemm256<<<grid12, 512, 131072, stream>>>(h1b, w2T, Yl, Yr, M, 512, nStrips, 4);
    gather_add_relu512<<<gblocks, 256, 0, stream>>>(Yl, Yr, b2, row_start,
                                                    csr_src, h2b, M);
    // ---- layer 3: Y3 = h2@[W3_l|W3_r]; out = lsm(gather(Y3l)+Y3r+b3) ----
    gemm256<<<grid3, 512, 131072, stream>>>(h2b, w3T, Yl, Yr, M, 128, nStrips, 1);
    gather_add_lsm128<<<g16blocks, 256, 0, stream>>>(Yl, Yr, b3, row_start,
                                                     csr_src, out, M);
}